// Round 1
// baseline (63.551 us; speedup 1.0000x reference)
//
#include <hip/hip_runtime.h>

using bf16x8 = __attribute__((ext_vector_type(8))) __bf16;
using f32x16 = __attribute__((ext_vector_type(16))) float;

#define BB 4
#define DD 64
#define LL 4096

// Kernel 1: x[b,l,d] = sum_k pe[b,k,l]*W[d,k] + bias[d]; xs = bf16(x/ls); h = 0.5*sum(xs^2)
__global__ __launch_bounds__(256) void prep_kernel(
    const float* __restrict__ pe,   // [B][D][L]
    const float* __restrict__ W,    // [D][D] row-major (out,in)
    const float* __restrict__ bias, // [D]
    const float* __restrict__ ls,   // scalar
    __bf16* __restrict__ xs,        // [B][L][D]
    float* __restrict__ h)          // [B][L]
{
    __shared__ float pe_lds[DD][64];
    __shared__ float W_lds[DD * DD];
    __shared__ float hpart[4][64];

    const int tid = threadIdx.x;
    const int blk = blockIdx.x;        // 256 blocks
    const int b  = blk >> 6;
    const int l0 = (blk & 63) * 64;

    // stage pe tile [64k x 64l] (coalesced) and W (16KB)
    {
        const int l = tid & 63;
        const int kb = tid >> 6;
        #pragma unroll
        for (int it = 0; it < 16; ++it) {
            const int k = it * 4 + kb;
            pe_lds[k][l] = pe[((size_t)b * DD + k) * LL + l0 + l];
        }
    }
    #pragma unroll
    for (int it = 0; it < 16; ++it)
        W_lds[it * 256 + tid] = W[it * 256 + tid];
    __syncthreads();

    const int w = tid >> 6;    // wave owns d-range [w*16, w*16+16)
    const int l = tid & 63;    // lane owns one l
    const float inv_ls = 1.0f / ls[0];

    float acc[16];
    #pragma unroll
    for (int i = 0; i < 16; ++i) acc[i] = bias[w * 16 + i];

    for (int k4 = 0; k4 < 16; ++k4) {
        const float p0 = pe_lds[k4 * 4 + 0][l];
        const float p1 = pe_lds[k4 * 4 + 1][l];
        const float p2 = pe_lds[k4 * 4 + 2][l];
        const float p3 = pe_lds[k4 * 4 + 3][l];
        #pragma unroll
        for (int i = 0; i < 16; ++i) {
            const float4 wv = *(const float4*)&W_lds[(w * 16 + i) * DD + k4 * 4];
            acc[i] += p0 * wv.x + p1 * wv.y + p2 * wv.z + p3 * wv.w;
        }
    }

    // bf16 round, h accumulated from the ROUNDED values (diagonal consistency)
    unsigned short out16[16];
    float hs = 0.0f;
    #pragma unroll
    for (int i = 0; i < 16; ++i) {
        const float xf = acc[i] * inv_ls;
        const __bf16 bv = (__bf16)xf;
        const float xr = (float)bv;
        hs += xr * xr;
        out16[i] = __builtin_bit_cast(unsigned short, bv);
    }
    {
        __bf16* dst = xs + ((size_t)b * LL + l0 + l) * DD + w * 16;
        *(uint4*)dst       = *(const uint4*)&out16[0];
        *(uint4*)(dst + 8) = *(const uint4*)&out16[8];
    }
    hpart[w][l] = hs;
    __syncthreads();
    if (tid < 64) {
        const float s = hpart[0][tid] + hpart[1][tid] + hpart[2][tid] + hpart[3][tid];
        h[(size_t)b * LL + l0 + tid] = 0.5f * s;
    }
}

// Kernel 2: per block one 128x128 output tile; 4 waves, 64x64 per wave;
// Gram via mfma_f32_32x32x16_bf16, xs served from L2 (512KB/batch), no LDS.
__global__ __launch_bounds__(256) void gram_kernel(
    const __bf16* __restrict__ xs,  // [B][L][D]
    const float* __restrict__ h,    // [B][L]
    const float* __restrict__ osc,  // scalar
    float* __restrict__ out)        // [B][L][L]
{
    const int bid = blockIdx.x;       // 4096 = 4 * 32 * 32
    const int b  = bid >> 10;
    const int t  = bid & 1023;
    const int ti = t >> 5, tj = t & 31;

    const int tid  = threadIdx.x;
    const int wid  = tid >> 6;
    const int lane = tid & 63;
    const int lr = lane & 31, lg = lane >> 5;

    const int rows0 = ti * 128 + (wid >> 1) * 64;
    const int cols0 = tj * 128 + (wid & 1) * 64;

    const __bf16* xsb = xs + (size_t)b * LL * DD;
    const float*  hb  = h + (size_t)b * LL;

    // A and B fragments loaded with IDENTICAL (lane,slot)->k formula -> any
    // hardware k-permutation yields the correct dot product (Gram bijection).
    bf16x8 af[2][4], bg[2][4];
    #pragma unroll
    for (int mt = 0; mt < 2; ++mt)
        #pragma unroll
        for (int kk = 0; kk < 4; ++kk)
            af[mt][kk] = *(const bf16x8*)(xsb + (size_t)(rows0 + mt * 32 + lr) * DD + kk * 16 + lg * 8);
    #pragma unroll
    for (int nt = 0; nt < 2; ++nt)
        #pragma unroll
        for (int kk = 0; kk < 4; ++kk)
            bg[nt][kk] = *(const bf16x8*)(xsb + (size_t)(cols0 + nt * 32 + lr) * DD + kk * 16 + lg * 8);

    f32x16 acc[2][2];
    #pragma unroll
    for (int mt = 0; mt < 2; ++mt)
        #pragma unroll
        for (int nt = 0; nt < 2; ++nt)
            acc[mt][nt] = (f32x16)(0.0f);

    #pragma unroll
    for (int kk = 0; kk < 4; ++kk)
        #pragma unroll
        for (int mt = 0; mt < 2; ++mt)
            #pragma unroll
            for (int nt = 0; nt < 2; ++nt)
                acc[mt][nt] = __builtin_amdgcn_mfma_f32_32x32x16_bf16(
                    af[mt][kk], bg[nt][kk], acc[mt][nt], 0, 0, 0);

    const float c = osc[0];
    const float LOG2E = 1.4426950408889634f;

    #pragma unroll
    for (int mt = 0; mt < 2; ++mt) {
        float hi[16];
        #pragma unroll
        for (int r = 0; r < 16; ++r)
            hi[r] = hb[rows0 + mt * 32 + (r & 3) + 8 * (r >> 2) + 4 * lg];
        #pragma unroll
        for (int nt = 0; nt < 2; ++nt) {
            const int col = cols0 + nt * 32 + lr;
            const float hj = hb[col];
            #pragma unroll
            for (int r = 0; r < 16; ++r) {
                const int row = rows0 + mt * 32 + (r & 3) + 8 * (r >> 2) + 4 * lg;
                float tt = acc[mt][nt][r] - hi[r] - hj;
                tt = fminf(tt, 0.0f);
                out[((size_t)b * LL + row) * LL + col] = c * __builtin_amdgcn_exp2f(tt * LOG2E);
            }
        }
    }
}

extern "C" void kernel_launch(void* const* d_in, const int* in_sizes, int n_in,
                              void* d_out, int out_size, void* d_ws, size_t ws_size,
                              hipStream_t stream) {
    const float* pe   = (const float*)d_in[0];
    const float* W    = (const float*)d_in[1];
    const float* bias = (const float*)d_in[2];
    const float* ls   = (const float*)d_in[3];
    const float* osc  = (const float*)d_in[4];
    float* out = (float*)d_out;

    __bf16* xs = (__bf16*)d_ws;                                       // 2 MiB
    float*  h  = (float*)((char*)d_ws + (size_t)BB * LL * DD * 2);    // 64 KiB

    prep_kernel<<<256, 256, 0, stream>>>(pe, W, bias, ls, xs, h);
    gram_kernel<<<BB * 32 * 32, 256, 0, stream>>>(xs, h, osc, out);
}